// Round 17
// baseline (200.077 us; speedup 1.0000x reference)
//
#include <hip/hip_runtime.h>

namespace {
constexpr int E_N  = 131072;
constexpr int FEA  = 256;
constexpr int RAD  = 64;
constexpr int HID  = 128;
constexpr int WN   = 256;
constexpr int EPB  = 128;   // edges per block
constexpr int NT   = 256;   // 4 waves; each wave owns 2 m-blocks (32 edges)
constexpr int LSTR = 68;    // len tile stride (floats), 16B-aligned
constexpr int ASTR = 132;   // act stride (floats), 16B-aligned rows
constexpr int SMEMF = EPB * ASTR;        // 16896 floats = 67584 B time-aliased
constexpr int FRAG_HI_SHORTS = 2 * 4 * 16 * 64 * 8;  // 65536: W2 hi, both pipes
constexpr int W1HI = 2 * FRAG_HI_SHORTS;             // 131072: W1 hi base
constexpr int W1LO_DELTA = 2 * 2 * 8 * 64 * 8;       // 16384 shorts
}

typedef short short8v __attribute__((ext_vector_type(8)));   // 8 bf16 (4 VGPRs)
typedef float floatx4 __attribute__((ext_vector_type(4)));   // MFMA accumulator

__device__ __forceinline__ unsigned bf16rne(float x) {       // f32 -> bf16 (RNE)
    const unsigned u = __float_as_uint(x);
    return (u + 0x7FFFu + ((u >> 16) & 1u)) >> 16;
}
__device__ __forceinline__ float bf16tof(unsigned h) {
    return __uint_as_float(h << 16);
}
__device__ __forceinline__ void bf16split(float x, unsigned& hi, unsigned& lo) {
    hi = bf16rne(x);
    lo = bf16rne(x - bf16tof(hi));
}

union FragU { uint4 u; short8v v; };

// ---- Prep: split W2 into bf16 hi/lo MFMA B-fragments in d_ws ----
// lane = s + 16*g holds k = 32*kt + 8*g + j, column nb*16 + s.
__global__ __launch_bounds__(64)
void prep_w2(const float* __restrict__ W2a, const float* __restrict__ W2b,
             unsigned short* __restrict__ frag)
{
    const int lane = threadIdx.x;
    const int nb = blockIdx.x, kt = blockIdx.y, pipe = blockIdx.z;
    const float* __restrict__ W2 = pipe ? W2b : W2a;
    const int g = lane >> 4, s = lane & 15;
    unsigned ph[4], pl[4];
    #pragma unroll
    for (int p = 0; p < 4; ++p) {
        const float x0 = W2[(size_t)(32*kt + 8*g + 2*p)     * WN + nb*16 + s];
        const float x1 = W2[(size_t)(32*kt + 8*g + 2*p + 1) * WN + nb*16 + s];
        unsigned h0, l0, h1, l1;
        bf16split(x0, h0, l0);
        bf16split(x1, h1, l1);
        ph[p] = h0 | (h1 << 16);
        pl[p] = l0 | (l1 << 16);
    }
    const size_t fi = (size_t)pipe * 32768 + (size_t)((kt*16 + nb)*64 + lane) * 8;
    *(uint4*)(frag + fi)                  = make_uint4(ph[0], ph[1], ph[2], ph[3]);
    *(uint4*)(frag + FRAG_HI_SHORTS + fi) = make_uint4(pl[0], pl[1], pl[2], pl[3]);
}

// ---- Prep: split W1 into bf16 hi/lo MFMA B-fragments (same convention) ----
__global__ __launch_bounds__(64)
void prep_w1(const float* __restrict__ W1a, const float* __restrict__ W1b,
             unsigned short* __restrict__ frag)
{
    const int lane = threadIdx.x;
    const int nb = blockIdx.x, kt = blockIdx.y, pipe = blockIdx.z;
    const float* __restrict__ W1 = pipe ? W1b : W1a;
    const int g = lane >> 4, s = lane & 15;
    unsigned ph[4], pl[4];
    #pragma unroll
    for (int p = 0; p < 4; ++p) {
        const float x0 = W1[(size_t)(32*kt + 8*g + 2*p)     * HID + nb*16 + s];
        const float x1 = W1[(size_t)(32*kt + 8*g + 2*p + 1) * HID + nb*16 + s];
        unsigned h0, l0, h1, l1;
        bf16split(x0, h0, l0);
        bf16split(x1, h1, l1);
        ph[p] = h0 | (h1 << 16);
        pl[p] = l0 | (l1 << 16);
    }
    const size_t fi = (size_t)W1HI + (size_t)pipe * 8192
                    + (size_t)((kt*8 + nb)*64 + lane) * 8;
    *(uint4*)(frag + fi)              = make_uint4(ph[0], ph[1], ph[2], ph[3]);
    *(uint4*)(frag + W1LO_DELTA + fi) = make_uint4(pl[0], pl[1], pl[2], pl[3]);
}

__global__ __launch_bounds__(NT, 2)
void fused_mlp_dtp(
    const float* __restrict__ fea_a, const float* __restrict__ vec_a,
    const float* __restrict__ len_a, const float* __restrict__ b1_a,
    const float* __restrict__ g_a,   const float* __restrict__ be_a,
    const float* __restrict__ fea_b, const float* __restrict__ vec_b,
    const float* __restrict__ len_b, const float* __restrict__ b1_b,
    const float* __restrict__ g_b,   const float* __restrict__ be_b,
    const unsigned short* __restrict__ fragW,
    float* __restrict__ out)
{
    // Time-aliased LDS (67584 B):
    //   phases 1-2: len f32[128][68] in [0, 34816)
    //   phases 3-4: act f32[128][132]
    //   epilogue:   stage 4 x 784 f32 in [0, 12544)
    __shared__ __align__(16) float smem[SMEMF];

    const int pipe = blockIdx.y;
    const float* __restrict__ fea = pipe ? fea_b : fea_a;
    const float* __restrict__ vec = pipe ? vec_b : vec_a;
    const float* __restrict__ len = pipe ? len_b : len_a;
    const float* __restrict__ b1  = pipe ? b1_b  : b1_a;
    const float* __restrict__ g   = pipe ? g_b   : g_a;
    const float* __restrict__ be  = pipe ? be_b  : be_a;
    float* __restrict__ outp = out + (size_t)pipe * (size_t)E_N * FEA;

    const int t    = threadIdx.x;
    const int lane = t & 63;
    const int wv_  = t >> 6;
    const int s_   = lane & 15, g_ = lane >> 4;
    const int ew   = wv_ * 32;              // wave's edge base within tile
    const long e0  = (long)blockIdx.x * EPB;

    // ---------- Phase 1: stage len tile [128][68] ----------
    {
        const float4* __restrict__ src = (const float4*)(len + e0 * RAD);
        #pragma unroll
        for (int i = 0; i < (EPB * RAD / 4) / NT; ++i) {
            const int f = t + i * NT;            // 0..2047
            const float4 v = src[f];
            const int e = f >> 4, kq = (f & 15) * 4;
            *(float4*)(&smem[e * LSTR + kq]) = v;
        }
    }
    __syncthreads();

    // ---------- Phase 2: h = len @ W1 via split-bf16 MFMA (2 m-blocks) ------
    floatx4 acc2[2][8];
    #pragma unroll
    for (int mb = 0; mb < 2; ++mb)
        #pragma unroll
        for (int nb = 0; nb < 8; ++nb) {
            acc2[mb][nb][0] = 0.f; acc2[mb][nb][1] = 0.f;
            acc2[mb][nb][2] = 0.f; acc2[mb][nb][3] = 0.f;
        }
    {
        const unsigned short* __restrict__ fH1 = fragW + W1HI + (size_t)pipe * 8192;
        const unsigned short* __restrict__ fL1 = fH1 + W1LO_DELTA;
        #pragma unroll
        for (int kt = 0; kt < 2; ++kt) {
            short8v ah[2], al[2];
            #pragma unroll
            for (int mb = 0; mb < 2; ++mb) {
                const int eA = ew + mb * 16 + s_;
                float xs[8];
                const float4 x0 = *(const float4*)(&smem[eA*LSTR + 32*kt + 8*g_]);
                const float4 x1 = *(const float4*)(&smem[eA*LSTR + 32*kt + 8*g_ + 4]);
                xs[0]=x0.x; xs[1]=x0.y; xs[2]=x0.z; xs[3]=x0.w;
                xs[4]=x1.x; xs[5]=x1.y; xs[6]=x1.z; xs[7]=x1.w;
                FragU ahu, alu;
                unsigned ph[4], pl[4];
                #pragma unroll
                for (int p = 0; p < 4; ++p) {
                    unsigned h0, l0, h1, l1;
                    bf16split(xs[2*p],     h0, l0);
                    bf16split(xs[2*p + 1], h1, l1);
                    ph[p] = h0 | (h1 << 16);
                    pl[p] = l0 | (l1 << 16);
                }
                ahu.u = make_uint4(ph[0], ph[1], ph[2], ph[3]);
                alu.u = make_uint4(pl[0], pl[1], pl[2], pl[3]);
                ah[mb] = ahu.v; al[mb] = alu.v;
            }
            const size_t kb = (size_t)(kt * 8) * 512 + (size_t)lane * 8;
            #pragma unroll
            for (int nb = 0; nb < 8; ++nb) {
                const short8v bh = *(const short8v*)(fH1 + kb + nb * 512);
                const short8v bl = *(const short8v*)(fL1 + kb + nb * 512);
                #pragma unroll
                for (int mb = 0; mb < 2; ++mb) {
                    acc2[mb][nb] = __builtin_amdgcn_mfma_f32_16x16x32_bf16(ah[mb], bh, acc2[mb][nb], 0, 0, 0);
                    acc2[mb][nb] = __builtin_amdgcn_mfma_f32_16x16x32_bf16(ah[mb], bl, acc2[mb][nb], 0, 0, 0);
                    acc2[mb][nb] = __builtin_amdgcn_mfma_f32_16x16x32_bf16(al[mb], bh, acc2[mb][nb], 0, 0, 0);
                }
            }
        }
    }
    __syncthreads();   // all len reads done; act region may now be written

    // ---------- Phase 3: b1 + LayerNorm + SiLU in registers, store act ------
    // C-layout: acc2[mb][nb][r] = h[edge ew+16mb+4g_+r][col 16nb+s_].
    {
        float hv[2][8][4];
        float sum[2][4], sq[2][4];
        #pragma unroll
        for (int mb = 0; mb < 2; ++mb)
            #pragma unroll
            for (int r = 0; r < 4; ++r) { sum[mb][r] = 0.f; sq[mb][r] = 0.f; }
        #pragma unroll
        for (int nb = 0; nb < 8; ++nb) {
            const float b1v = b1[16*nb + s_];
            #pragma unroll
            for (int mb = 0; mb < 2; ++mb)
                #pragma unroll
                for (int r = 0; r < 4; ++r) {
                    const float v = acc2[mb][nb][r] + b1v;
                    hv[mb][nb][r] = v;
                    sum[mb][r] += v;
                    sq [mb][r] += v * v;
                }
        }
        float mu[2][4], iv[2][4];
        #pragma unroll
        for (int mb = 0; mb < 2; ++mb)
            #pragma unroll
            for (int r = 0; r < 4; ++r) {
                float s1 = sum[mb][r], s2 = sq[mb][r];
                s1 += __shfl_xor(s1, 1); s1 += __shfl_xor(s1, 2);
                s1 += __shfl_xor(s1, 4); s1 += __shfl_xor(s1, 8);
                s2 += __shfl_xor(s2, 1); s2 += __shfl_xor(s2, 2);
                s2 += __shfl_xor(s2, 4); s2 += __shfl_xor(s2, 8);
                mu[mb][r] = s1 * (1.0f / HID);
                float var = s2 * (1.0f / HID) - mu[mb][r] * mu[mb][r];
                var = fmaxf(var, 0.0f);
                iv[mb][r] = rsqrtf(var + 1e-5f);
            }
        #pragma unroll
        for (int nb = 0; nb < 8; ++nb) {
            const float gv  = g [16*nb + s_];
            const float bev = be[16*nb + s_];
            #pragma unroll
            for (int mb = 0; mb < 2; ++mb) {
                const int rowb = ew + 16*mb + 4*g_;
                #pragma unroll
                for (int r = 0; r < 4; ++r) {
                    const float hn = (hv[mb][nb][r] - mu[mb][r]) * iv[mb][r] * gv + bev;
                    const float sl = hn / (1.0f + __expf(-hn));
                    smem[(rowb + r) * ASTR + 16*nb + s_] = sl;   // 2-way, free
                }
            }
        }
    }
    __syncthreads();

    // ---------- Phase 4: w = silu @ W2 via split-bf16 MFMA (2 m-blocks) -----
    floatx4 acc[2][16];
    #pragma unroll
    for (int mb = 0; mb < 2; ++mb)
        #pragma unroll
        for (int nb = 0; nb < 16; ++nb) {
            acc[mb][nb][0] = 0.f; acc[mb][nb][1] = 0.f;
            acc[mb][nb][2] = 0.f; acc[mb][nb][3] = 0.f;
        }
    {
        const unsigned short* __restrict__ fH = fragW + (size_t)pipe * 32768;
        const unsigned short* __restrict__ fL = fH + FRAG_HI_SHORTS;
        for (int kt = 0; kt < 4; ++kt) {
            short8v ah[2], al[2];
            #pragma unroll
            for (int mb = 0; mb < 2; ++mb) {
                const int eA = ew + mb * 16 + s_;
                float xs[8];
                const float4 x0 = *(const float4*)(&smem[eA*ASTR + 32*kt + 8*g_]);
                const float4 x1 = *(const float4*)(&smem[eA*ASTR + 32*kt + 8*g_ + 4]);
                xs[0]=x0.x; xs[1]=x0.y; xs[2]=x0.z; xs[3]=x0.w;
                xs[4]=x1.x; xs[5]=x1.y; xs[6]=x1.z; xs[7]=x1.w;
                FragU ahu, alu;
                unsigned ph[4], pl[4];
                #pragma unroll
                for (int p = 0; p < 4; ++p) {
                    unsigned h0, l0, h1, l1;
                    bf16split(xs[2*p],     h0, l0);
                    bf16split(xs[2*p + 1], h1, l1);
                    ph[p] = h0 | (h1 << 16);
                    pl[p] = l0 | (l1 << 16);
                }
                ahu.u = make_uint4(ph[0], ph[1], ph[2], ph[3]);
                alu.u = make_uint4(pl[0], pl[1], pl[2], pl[3]);
                ah[mb] = ahu.v; al[mb] = alu.v;
            }
            const size_t kb = (size_t)(kt * 16) * 512 + (size_t)lane * 8;
            #pragma unroll
            for (int nb = 0; nb < 16; ++nb) {
                const short8v bh = *(const short8v*)(fH + kb + nb * 512);
                const short8v bl = *(const short8v*)(fL + kb + nb * 512);
                #pragma unroll
                for (int mb = 0; mb < 2; ++mb) {
                    acc[mb][nb] = __builtin_amdgcn_mfma_f32_16x16x32_bf16(ah[mb], bh, acc[mb][nb], 0, 0, 0);
                    acc[mb][nb] = __builtin_amdgcn_mfma_f32_16x16x32_bf16(ah[mb], bl, acc[mb][nb], 0, 0, 0);
                    acc[mb][nb] = __builtin_amdgcn_mfma_f32_16x16x32_bf16(al[mb], bh, acc[mb][nb], 0, 0, 0);
                }
            }
        }
    }
    __syncthreads();   // all act reads done; region becomes epilogue stage

    // ---------- Epilogue: DTP from C-layout (r14 structure, 2 m-blocks) -----
    {
        const float c2 = 0.70710678118654752f;   // 1/sqrt(2)
        const float c3 = 0.40824829046386302f;   // 1/sqrt(6)
        float* sStage = smem + wv_ * 784;        // [4 g-groups][196], per-wave
        #pragma unroll
        for (int mb = 0; mb < 2; ++mb) {
            for (int r = 0; r < 4; ++r) {
                const long e = e0 + ew + 16*mb + 4*g_ + r;
                const float4 y = *(const float4*)(vec + e * 4);
                const float* __restrict__ fr   = fea  + e * (size_t)FEA;
                float* __restrict__       orow = outp + e * (size_t)FEA;
                #pragma unroll
                for (int q = 0; q < 4; ++q) {
                    const int u = 16 * q + s_;
                    const float w1 = acc[mb][q     ][r];
                    const float w2 = acc[mb][q + 4 ][r];
                    const float w3 = acc[mb][q + 8 ][r];
                    const float w4 = acc[mb][q + 12][r];
                    const float x0  = fr[u];
                    const float x1a = fr[64 + 3*u + 0];
                    const float x1b = fr[64 + 3*u + 1];
                    const float x1c = fr[64 + 3*u + 2];
                    const float dot = x1a*y.y + x1b*y.z + x1c*y.w;
                    orow[u] = w1*x0*y.x*c2 + w4*dot*c3;
                    sStage[g_*196 + 3*u + 0] = (w2*x0*y.y + w3*x1a*y.x) * c2;
                    sStage[g_*196 + 3*u + 1] = (w2*x0*y.z + w3*x1b*y.x) * c2;
                    sStage[g_*196 + 3*u + 2] = (w2*x0*y.w + w3*x1c*y.x) * c2;
                }
                __syncthreads();   // stage complete (convergent: all waves, mb, r)
                #pragma unroll
                for (int rr = 0; rr < 3; ++rr) {
                    const int flat = rr * 256 + lane * 4;     // 0..764
                    const int eloc = flat / 192;              // 0..3 (g-group)
                    const int pos  = flat % 192;              // 16B aligned
                    const float4 v = *(const float4*)(&sStage[eloc * 196 + pos]);
                    *(float4*)(&outp[(e0 + ew + 16*mb + 4*eloc + r) * (size_t)FEA + 64 + pos]) = v;
                }
                __syncthreads();   // drain complete before next iter overwrites
            }
        }
    }
}

extern "C" void kernel_launch(void* const* d_in, const int* in_sizes, int n_in,
                              void* d_out, int out_size, void* d_ws, size_t ws_size,
                              hipStream_t stream) {
    (void)in_sizes; (void)n_in; (void)ws_size; (void)out_size;
    const float* fea_a = (const float*)d_in[0];
    const float* vec_a = (const float*)d_in[1];
    const float* len_a = (const float*)d_in[2];
    const float* W1_a  = (const float*)d_in[3];
    const float* b1_a  = (const float*)d_in[4];
    const float* g_a   = (const float*)d_in[5];
    const float* be_a  = (const float*)d_in[6];
    const float* W2_a  = (const float*)d_in[7];
    const float* fea_b = (const float*)d_in[8];
    const float* vec_b = (const float*)d_in[9];
    const float* len_b = (const float*)d_in[10];
    const float* W1_b  = (const float*)d_in[11];
    const float* b1_b  = (const float*)d_in[12];
    const float* g_b   = (const float*)d_in[13];
    const float* be_b  = (const float*)d_in[14];
    const float* W2_b  = (const float*)d_in[15];
    float* out = (float*)d_out;
    unsigned short* frag = (unsigned short*)d_ws;   // needs 320 KB

    hipLaunchKernelGGL(prep_w2, dim3(16, 4, 2), dim3(64), 0, stream,
                       W2_a, W2_b, frag);
    hipLaunchKernelGGL(prep_w1, dim3(8, 2, 2), dim3(64), 0, stream,
                       W1_a, W1_b, frag);

    dim3 grid(E_N / EPB, 2);
    dim3 block(NT);
    hipLaunchKernelGGL(fused_mlp_dtp, grid, block, 0, stream,
                       fea_a, vec_a, len_a, b1_a, g_a, be_a,
                       fea_b, vec_b, len_b, b1_b, g_b, be_b,
                       frag, out);
}

// Round 18
// 191.552 us; speedup vs baseline: 1.0445x; 1.0445x over previous
//
#include <hip/hip_runtime.h>

namespace {
constexpr int E_N  = 131072;
constexpr int FEA  = 256;
constexpr int RAD  = 64;
constexpr int HID  = 128;
constexpr int WN   = 256;
constexpr int EPB  = 64;    // edges per block
constexpr int NT   = 256;   // 4 waves
constexpr int ASTR = 132;   // act stride (floats), 16B-aligned rows
constexpr int SMEMF = EPB * ASTR;        // 8448 floats = 33792 B
constexpr int FRAG_HI_SHORTS = 2 * 4 * 16 * 64 * 8;  // 65536: W2 hi, both pipes
constexpr int W1HI = 2 * FRAG_HI_SHORTS;             // 131072: W1 hi base
constexpr int W1LO_DELTA = 2 * 2 * 8 * 64 * 8;       // 16384 shorts
}

typedef short short8v __attribute__((ext_vector_type(8)));   // 8 bf16 (4 VGPRs)
typedef float floatx4 __attribute__((ext_vector_type(4)));   // MFMA accumulator

__device__ __forceinline__ unsigned bf16rne(float x) {       // f32 -> bf16 (RNE)
    const unsigned u = __float_as_uint(x);
    return (u + 0x7FFFu + ((u >> 16) & 1u)) >> 16;
}
__device__ __forceinline__ float bf16tof(unsigned h) {
    return __uint_as_float(h << 16);
}
__device__ __forceinline__ void bf16split(float x, unsigned& hi, unsigned& lo) {
    hi = bf16rne(x);
    lo = bf16rne(x - bf16tof(hi));
}

union FragU { uint4 u; short8v v; };

// ---- Prep: split W2 into bf16 hi/lo MFMA B-fragments in d_ws ----
// lane = s + 16*g holds k = 32*kt + 8*g + j, column nb*16 + s.
__global__ __launch_bounds__(64)
void prep_w2(const float* __restrict__ W2a, const float* __restrict__ W2b,
             unsigned short* __restrict__ frag)
{
    const int lane = threadIdx.x;
    const int nb = blockIdx.x, kt = blockIdx.y, pipe = blockIdx.z;
    const float* __restrict__ W2 = pipe ? W2b : W2a;
    const int g = lane >> 4, s = lane & 15;
    unsigned ph[4], pl[4];
    #pragma unroll
    for (int p = 0; p < 4; ++p) {
        const float x0 = W2[(size_t)(32*kt + 8*g + 2*p)     * WN + nb*16 + s];
        const float x1 = W2[(size_t)(32*kt + 8*g + 2*p + 1) * WN + nb*16 + s];
        unsigned h0, l0, h1, l1;
        bf16split(x0, h0, l0);
        bf16split(x1, h1, l1);
        ph[p] = h0 | (h1 << 16);
        pl[p] = l0 | (l1 << 16);
    }
    const size_t fi = (size_t)pipe * 32768 + (size_t)((kt*16 + nb)*64 + lane) * 8;
    *(uint4*)(frag + fi)                  = make_uint4(ph[0], ph[1], ph[2], ph[3]);
    *(uint4*)(frag + FRAG_HI_SHORTS + fi) = make_uint4(pl[0], pl[1], pl[2], pl[3]);
}

// ---- Prep: split W1 into bf16 hi/lo MFMA B-fragments (same convention) ----
__global__ __launch_bounds__(64)
void prep_w1(const float* __restrict__ W1a, const float* __restrict__ W1b,
             unsigned short* __restrict__ frag)
{
    const int lane = threadIdx.x;
    const int nb = blockIdx.x, kt = blockIdx.y, pipe = blockIdx.z;
    const float* __restrict__ W1 = pipe ? W1b : W1a;
    const int g = lane >> 4, s = lane & 15;
    unsigned ph[4], pl[4];
    #pragma unroll
    for (int p = 0; p < 4; ++p) {
        const float x0 = W1[(size_t)(32*kt + 8*g + 2*p)     * HID + nb*16 + s];
        const float x1 = W1[(size_t)(32*kt + 8*g + 2*p + 1) * HID + nb*16 + s];
        unsigned h0, l0, h1, l1;
        bf16split(x0, h0, l0);
        bf16split(x1, h1, l1);
        ph[p] = h0 | (h1 << 16);
        pl[p] = l0 | (l1 << 16);
    }
    const size_t fi = (size_t)W1HI + (size_t)pipe * 8192
                    + (size_t)((kt*8 + nb)*64 + lane) * 8;
    *(uint4*)(frag + fi)              = make_uint4(ph[0], ph[1], ph[2], ph[3]);
    *(uint4*)(frag + W1LO_DELTA + fi) = make_uint4(pl[0], pl[1], pl[2], pl[3]);
}

__global__ __launch_bounds__(NT, 4)
void fused_mlp_dtp(
    const float* __restrict__ fea_a, const float* __restrict__ vec_a,
    const float* __restrict__ len_a, const float* __restrict__ b1_a,
    const float* __restrict__ g_a,   const float* __restrict__ be_a,
    const float* __restrict__ fea_b, const float* __restrict__ vec_b,
    const float* __restrict__ len_b, const float* __restrict__ b1_b,
    const float* __restrict__ g_b,   const float* __restrict__ be_b,
    const unsigned short* __restrict__ fragW,
    float* __restrict__ out)
{
    // LDS (33792 B): act f32[64][132]; epilogue stage (25088 B) aliased after
    // the phase-4 barrier.
    __shared__ __align__(16) float smem[SMEMF];

    const int pipe = blockIdx.y;
    const float* __restrict__ fea = pipe ? fea_b : fea_a;
    const float* __restrict__ vec = pipe ? vec_b : vec_a;
    const float* __restrict__ len = pipe ? len_b : len_a;
    const float* __restrict__ b1  = pipe ? b1_b  : b1_a;
    const float* __restrict__ g   = pipe ? g_b   : g_a;
    const float* __restrict__ be  = pipe ? be_b  : be_a;
    float* __restrict__ outp = out + (size_t)pipe * (size_t)E_N * FEA;

    const int t    = threadIdx.x;
    const int lane = t & 63;
    const int wv_  = t >> 6;
    const int s_   = lane & 15, g_ = lane >> 4;
    const long e0  = (long)blockIdx.x * EPB;

    // ---------- Phase 2: h = len @ W1 via split-bf16 MFMA (A from global) ---
    // Lane (s_,g_) reads len[e0+16w+s_][32kt+8g_ .. +8): wave touches 16 rows
    // x 128B contiguous -> fully coalesced; len read exactly once per block.
    floatx4 acc2[8];
    #pragma unroll
    for (int nb = 0; nb < 8; ++nb) {
        acc2[nb][0] = 0.f; acc2[nb][1] = 0.f; acc2[nb][2] = 0.f; acc2[nb][3] = 0.f;
    }
    {
        const float* __restrict__ lrow = len + (e0 + wv_ * 16 + s_) * (size_t)RAD;
        const unsigned short* __restrict__ fH1 = fragW + W1HI + (size_t)pipe * 8192;
        const unsigned short* __restrict__ fL1 = fH1 + W1LO_DELTA;
        #pragma unroll
        for (int kt = 0; kt < 2; ++kt) {
            float xs[8];
            {
                const float4 x0 = *(const float4*)(lrow + 32*kt + 8*g_);
                const float4 x1 = *(const float4*)(lrow + 32*kt + 8*g_ + 4);
                xs[0]=x0.x; xs[1]=x0.y; xs[2]=x0.z; xs[3]=x0.w;
                xs[4]=x1.x; xs[5]=x1.y; xs[6]=x1.z; xs[7]=x1.w;
            }
            FragU ahu, alu;
            {
                unsigned ph[4], pl[4];
                #pragma unroll
                for (int p = 0; p < 4; ++p) {
                    unsigned h0, l0, h1, l1;
                    bf16split(xs[2*p],     h0, l0);
                    bf16split(xs[2*p + 1], h1, l1);
                    ph[p] = h0 | (h1 << 16);
                    pl[p] = l0 | (l1 << 16);
                }
                ahu.u = make_uint4(ph[0], ph[1], ph[2], ph[3]);
                alu.u = make_uint4(pl[0], pl[1], pl[2], pl[3]);
            }
            const short8v ah = ahu.v, al = alu.v;
            const size_t kb = (size_t)(kt * 8) * 512 + (size_t)lane * 8;
            #pragma unroll
            for (int nb = 0; nb < 8; ++nb) {
                const short8v bh = *(const short8v*)(fH1 + kb + nb * 512);
                const short8v bl = *(const short8v*)(fL1 + kb + nb * 512);
                acc2[nb] = __builtin_amdgcn_mfma_f32_16x16x32_bf16(ah, bh, acc2[nb], 0, 0, 0);
                acc2[nb] = __builtin_amdgcn_mfma_f32_16x16x32_bf16(ah, bl, acc2[nb], 0, 0, 0);
                acc2[nb] = __builtin_amdgcn_mfma_f32_16x16x32_bf16(al, bh, acc2[nb], 0, 0, 0);
            }
        }
    }
    // No barrier: act region untouched so far; phase 3 writes only this
    // wave's own rows.

    // ---------- Phase 3: b1 + LayerNorm + SiLU in registers, store act ------
    // C-layout: acc2[nb][r] = h[edge 16w+4g_+r][col 16nb+s_].
    {
        float hv[8][4];
        float sum[4] = {0.f, 0.f, 0.f, 0.f};
        float sq [4] = {0.f, 0.f, 0.f, 0.f};
        #pragma unroll
        for (int nb = 0; nb < 8; ++nb) {
            const float b1v = b1[16*nb + s_];
            #pragma unroll
            for (int r = 0; r < 4; ++r) {
                const float v = acc2[nb][r] + b1v;
                hv[nb][r] = v;
                sum[r] += v;
                sq [r] += v * v;
            }
        }
        float mu[4], iv[4];
        #pragma unroll
        for (int r = 0; r < 4; ++r) {
            float s1 = sum[r], s2 = sq[r];
            s1 += __shfl_xor(s1, 1); s1 += __shfl_xor(s1, 2);
            s1 += __shfl_xor(s1, 4); s1 += __shfl_xor(s1, 8);
            s2 += __shfl_xor(s2, 1); s2 += __shfl_xor(s2, 2);
            s2 += __shfl_xor(s2, 4); s2 += __shfl_xor(s2, 8);
            mu[r] = s1 * (1.0f / HID);
            float var = s2 * (1.0f / HID) - mu[r] * mu[r];
            var = fmaxf(var, 0.0f);
            iv[r] = rsqrtf(var + 1e-5f);
        }
        const int rowb = wv_ * 16 + 4 * g_;
        #pragma unroll
        for (int nb = 0; nb < 8; ++nb) {
            const float gv  = g [16*nb + s_];
            const float bev = be[16*nb + s_];
            #pragma unroll
            for (int r = 0; r < 4; ++r) {
                const float hn = (hv[nb][r] - mu[r]) * iv[r] * gv + bev;
                const float sl = hn / (1.0f + __expf(-hn));
                smem[(rowb + r) * ASTR + 16*nb + s_] = sl;   // 2-way, free
            }
        }
    }
    __syncthreads();   // act visible (intra-wave redistribution via LDS)

    // ---------- Phase 4: w = silu @ W2 via split-bf16 MFMA (r14 verbatim) ---
    floatx4 acc[16];
    #pragma unroll
    for (int nb = 0; nb < 16; ++nb) {
        acc[nb][0] = 0.f; acc[nb][1] = 0.f; acc[nb][2] = 0.f; acc[nb][3] = 0.f;
    }
    {
        const int eA = wv_ * 16 + s_;
        const unsigned short* __restrict__ fH = fragW + (size_t)pipe * 32768;
        const unsigned short* __restrict__ fL = fH + FRAG_HI_SHORTS;
        for (int kt = 0; kt < 4; ++kt) {
            float xs[8];
            {
                const float4 x0 = *(const float4*)(&smem[eA*ASTR + 32*kt + 8*g_]);
                const float4 x1 = *(const float4*)(&smem[eA*ASTR + 32*kt + 8*g_ + 4]);
                xs[0]=x0.x; xs[1]=x0.y; xs[2]=x0.z; xs[3]=x0.w;
                xs[4]=x1.x; xs[5]=x1.y; xs[6]=x1.z; xs[7]=x1.w;
            }
            FragU ahu, alu;
            {
                unsigned ph[4], pl[4];
                #pragma unroll
                for (int p = 0; p < 4; ++p) {
                    unsigned h0, l0, h1, l1;
                    bf16split(xs[2*p],     h0, l0);
                    bf16split(xs[2*p + 1], h1, l1);
                    ph[p] = h0 | (h1 << 16);
                    pl[p] = l0 | (l1 << 16);
                }
                ahu.u = make_uint4(ph[0], ph[1], ph[2], ph[3]);
                alu.u = make_uint4(pl[0], pl[1], pl[2], pl[3]);
            }
            const short8v ah = ahu.v, al = alu.v;
            const size_t kb = (size_t)(kt * 16) * 512 + (size_t)lane * 8;
            #pragma unroll
            for (int nb = 0; nb < 16; ++nb) {
                const short8v bh = *(const short8v*)(fH + kb + nb * 512);
                const short8v bl = *(const short8v*)(fL + kb + nb * 512);
                acc[nb] = __builtin_amdgcn_mfma_f32_16x16x32_bf16(ah, bh, acc[nb], 0, 0, 0);
                acc[nb] = __builtin_amdgcn_mfma_f32_16x16x32_bf16(ah, bl, acc[nb], 0, 0, 0);
                acc[nb] = __builtin_amdgcn_mfma_f32_16x16x32_bf16(al, bh, acc[nb], 0, 0, 0);
            }
        }
    }
    __syncthreads();   // all act reads done; region becomes epilogue stage

    // ---------- Epilogue: DTP from C-layout; 2 r-iterations per barrier -----
    {
        const float c2 = 0.70710678118654752f;   // 1/sqrt(2)
        const float c3 = 0.40824829046386302f;   // 1/sqrt(6)
        float* sStage = smem + wv_ * 1568;       // [2 r][4 g-groups][196]
        for (int rp = 0; rp < 2; ++rp) {
            #pragma unroll
            for (int rr = 0; rr < 2; ++rr) {
                const int r = rp * 2 + rr;
                const long e = e0 + wv_ * 16 + 4 * g_ + r;
                const float4 y = *(const float4*)(vec + e * 4);
                const float* __restrict__ fr   = fea  + e * (size_t)FEA;
                float* __restrict__       orow = outp + e * (size_t)FEA;
                #pragma unroll
                for (int q = 0; q < 4; ++q) {
                    const int u = 16 * q + s_;
                    const float w1 = acc[q     ][r];
                    const float w2 = acc[q + 4 ][r];
                    const float w3 = acc[q + 8 ][r];
                    const float w4 = acc[q + 12][r];
                    const float x0  = fr[u];
                    const float x1a = fr[64 + 3*u + 0];
                    const float x1b = fr[64 + 3*u + 1];
                    const float x1c = fr[64 + 3*u + 2];
                    const float dot = x1a*y.y + x1b*y.z + x1c*y.w;
                    orow[u] = w1*x0*y.x*c2 + w4*dot*c3;
                    sStage[rr*784 + g_*196 + 3*u + 0] = (w2*x0*y.y + w3*x1a*y.x) * c2;
                    sStage[rr*784 + g_*196 + 3*u + 1] = (w2*x0*y.z + w3*x1b*y.x) * c2;
                    sStage[rr*784 + g_*196 + 3*u + 2] = (w2*x0*y.w + w3*x1c*y.x) * c2;
                }
            }
            __syncthreads();   // stage complete (convergent: all waves, all rp)
            #pragma unroll
            for (int rr = 0; rr < 2; ++rr)
                #pragma unroll
                for (int dd = 0; dd < 3; ++dd) {
                    const int flat = dd * 256 + lane * 4;     // 0..764
                    const int eloc = flat / 192;              // 0..3 (g-group)
                    const int pos  = flat % 192;              // 16B aligned
                    const float4 v = *(const float4*)(&sStage[rr*784 + eloc*196 + pos]);
                    *(float4*)(&outp[(e0 + wv_*16 + 4*eloc + rp*2 + rr) * (size_t)FEA + 64 + pos]) = v;
                }
            __syncthreads();   // drain complete before next rp overwrites
        }
    }
}

extern "C" void kernel_launch(void* const* d_in, const int* in_sizes, int n_in,
                              void* d_out, int out_size, void* d_ws, size_t ws_size,
                              hipStream_t stream) {
    (void)in_sizes; (void)n_in; (void)ws_size; (void)out_size;
    const float* fea_a = (const float*)d_in[0];
    const float* vec_a = (const float*)d_in[1];
    const float* len_a = (const float*)d_in[2];
    const float* W1_a  = (const float*)d_in[3];
    const float* b1_a  = (const float*)d_in[4];
    const float* g_a   = (const float*)d_in[5];
    const float* be_a  = (const float*)d_in[6];
    const float* W2_a  = (const float*)d_in[7];
    const float* fea_b = (const float*)d_in[8];
    const float* vec_b = (const float*)d_in[9];
    const float* len_b = (const float*)d_in[10];
    const float* W1_b  = (const float*)d_in[11];
    const float* b1_b  = (const float*)d_in[12];
    const float* g_b   = (const float*)d_in[13];
    const float* be_b  = (const float*)d_in[14];
    const float* W2_b  = (const float*)d_in[15];
    float* out = (float*)d_out;
    unsigned short* frag = (unsigned short*)d_ws;   // needs 320 KB

    hipLaunchKernelGGL(prep_w2, dim3(16, 4, 2), dim3(64), 0, stream,
                       W2_a, W2_b, frag);
    hipLaunchKernelGGL(prep_w1, dim3(8, 2, 2), dim3(64), 0, stream,
                       W1_a, W1_b, frag);

    dim3 grid(E_N / EPB, 2);
    dim3 block(NT);
    hipLaunchKernelGGL(fused_mlp_dtp, grid, block, 0, stream,
                       fea_a, vec_a, len_a, b1_a, g_a, be_a,
                       fea_b, vec_b, len_b, b1_b, g_b, be_b,
                       frag, out);
}

// Round 19
// 190.543 us; speedup vs baseline: 1.0500x; 1.0053x over previous
//
#include <hip/hip_runtime.h>

namespace {
constexpr int E_N  = 131072;
constexpr int FEA  = 256;
constexpr int RAD  = 64;
constexpr int HID  = 128;
constexpr int WN   = 256;
constexpr int EPB  = 64;    // edges per block
constexpr int NT   = 256;   // 4 waves
constexpr int LSTR = 68;    // len tile stride (floats), 16B-aligned
constexpr int ASTR = 132;   // act stride (floats), 16B-aligned rows
constexpr int SMEMF = EPB * ASTR;        // 8448 floats = 33792 B time-aliased
constexpr int FRAG_HI_SHORTS = 2 * 4 * 16 * 64 * 8;  // 65536: W2 hi, both pipes
constexpr int W1HI = 2 * FRAG_HI_SHORTS;             // 131072: W1 hi base
constexpr int W1LO_DELTA = 2 * 2 * 8 * 64 * 8;       // 16384 shorts
}

typedef short short8v __attribute__((ext_vector_type(8)));   // 8 bf16 (4 VGPRs)
typedef float floatx4 __attribute__((ext_vector_type(4)));   // MFMA accumulator

__device__ __forceinline__ unsigned bf16rne(float x) {       // f32 -> bf16 (RNE)
    const unsigned u = __float_as_uint(x);
    return (u + 0x7FFFu + ((u >> 16) & 1u)) >> 16;
}
__device__ __forceinline__ float bf16tof(unsigned h) {
    return __uint_as_float(h << 16);
}
__device__ __forceinline__ void bf16split(float x, unsigned& hi, unsigned& lo) {
    hi = bf16rne(x);
    lo = bf16rne(x - bf16tof(hi));
}

union FragU { uint4 u; short8v v; };

// ---- Prep: split W2 into bf16 hi/lo MFMA B-fragments in d_ws ----
// lane = s + 16*g holds k = 32*kt + 8*g + j, column nb*16 + s.
__global__ __launch_bounds__(64)
void prep_w2(const float* __restrict__ W2a, const float* __restrict__ W2b,
             unsigned short* __restrict__ frag)
{
    const int lane = threadIdx.x;
    const int nb = blockIdx.x, kt = blockIdx.y, pipe = blockIdx.z;
    const float* __restrict__ W2 = pipe ? W2b : W2a;
    const int g = lane >> 4, s = lane & 15;
    unsigned ph[4], pl[4];
    #pragma unroll
    for (int p = 0; p < 4; ++p) {
        const float x0 = W2[(size_t)(32*kt + 8*g + 2*p)     * WN + nb*16 + s];
        const float x1 = W2[(size_t)(32*kt + 8*g + 2*p + 1) * WN + nb*16 + s];
        unsigned h0, l0, h1, l1;
        bf16split(x0, h0, l0);
        bf16split(x1, h1, l1);
        ph[p] = h0 | (h1 << 16);
        pl[p] = l0 | (l1 << 16);
    }
    const size_t fi = (size_t)pipe * 32768 + (size_t)((kt*16 + nb)*64 + lane) * 8;
    *(uint4*)(frag + fi)                  = make_uint4(ph[0], ph[1], ph[2], ph[3]);
    *(uint4*)(frag + FRAG_HI_SHORTS + fi) = make_uint4(pl[0], pl[1], pl[2], pl[3]);
}

// ---- Prep: split W1 into bf16 hi/lo MFMA B-fragments (same convention) ----
__global__ __launch_bounds__(64)
void prep_w1(const float* __restrict__ W1a, const float* __restrict__ W1b,
             unsigned short* __restrict__ frag)
{
    const int lane = threadIdx.x;
    const int nb = blockIdx.x, kt = blockIdx.y, pipe = blockIdx.z;
    const float* __restrict__ W1 = pipe ? W1b : W1a;
    const int g = lane >> 4, s = lane & 15;
    unsigned ph[4], pl[4];
    #pragma unroll
    for (int p = 0; p < 4; ++p) {
        const float x0 = W1[(size_t)(32*kt + 8*g + 2*p)     * HID + nb*16 + s];
        const float x1 = W1[(size_t)(32*kt + 8*g + 2*p + 1) * HID + nb*16 + s];
        unsigned h0, l0, h1, l1;
        bf16split(x0, h0, l0);
        bf16split(x1, h1, l1);
        ph[p] = h0 | (h1 << 16);
        pl[p] = l0 | (l1 << 16);
    }
    const size_t fi = (size_t)W1HI + (size_t)pipe * 8192
                    + (size_t)((kt*8 + nb)*64 + lane) * 8;
    *(uint4*)(frag + fi)              = make_uint4(ph[0], ph[1], ph[2], ph[3]);
    *(uint4*)(frag + W1LO_DELTA + fi) = make_uint4(pl[0], pl[1], pl[2], pl[3]);
}

__global__ __launch_bounds__(NT, 4)
void fused_mlp_dtp(
    const float* __restrict__ fea_a, const float* __restrict__ vec_a,
    const float* __restrict__ len_a, const float* __restrict__ b1_a,
    const float* __restrict__ g_a,   const float* __restrict__ be_a,
    const float* __restrict__ fea_b, const float* __restrict__ vec_b,
    const float* __restrict__ len_b, const float* __restrict__ b1_b,
    const float* __restrict__ g_b,   const float* __restrict__ be_b,
    const unsigned short* __restrict__ fragW,
    float* __restrict__ out)
{
    // Time-aliased LDS (33792 B): len[64][68] -> act[64][132] -> epi stage
    __shared__ __align__(16) float smem[SMEMF];

    const int pipe = blockIdx.y;
    const float* __restrict__ fea = pipe ? fea_b : fea_a;
    const float* __restrict__ vec = pipe ? vec_b : vec_a;
    const float* __restrict__ len = pipe ? len_b : len_a;
    const float* __restrict__ b1  = pipe ? b1_b  : b1_a;
    const float* __restrict__ g   = pipe ? g_b   : g_a;
    const float* __restrict__ be  = pipe ? be_b  : be_a;
    float* __restrict__ outp = out + (size_t)pipe * (size_t)E_N * FEA;

    const int t    = threadIdx.x;
    const int lane = t & 63;
    const int wv_  = t >> 6;
    const int s_   = lane & 15, g_ = lane >> 4;
    const long e0  = (long)blockIdx.x * EPB;

    // ---------- Phase 1: stage len tile [64][68] ----------
    {
        const float4* __restrict__ src = (const float4*)(len + e0 * RAD);
        #pragma unroll
        for (int i = 0; i < (EPB * RAD / 4) / NT; ++i) {
            const int f = t + i * NT;            // 0..1023
            const float4 v = src[f];
            const int e = f >> 4, kq = (f & 15) * 4;
            *(float4*)(&smem[e * LSTR + kq]) = v;
        }
    }
    __syncthreads();

    // ---------- Phase 2: h = len @ W1 via split-bf16 MFMA ----------
    // Wave owns edges [16w,16w+16); acc2[nb] covers cols [16nb,16nb+16).
    floatx4 acc2[8];
    #pragma unroll
    for (int nb = 0; nb < 8; ++nb) {
        acc2[nb][0] = 0.f; acc2[nb][1] = 0.f; acc2[nb][2] = 0.f; acc2[nb][3] = 0.f;
    }
    {
        const int eA = wv_ * 16 + s_;
        const unsigned short* __restrict__ fH1 = fragW + W1HI + (size_t)pipe * 8192;
        const unsigned short* __restrict__ fL1 = fH1 + W1LO_DELTA;
        #pragma unroll
        for (int kt = 0; kt < 2; ++kt) {
            float xs[8];
            {
                const float4 x0 = *(const float4*)(&smem[eA*LSTR + 32*kt + 8*g_]);
                const float4 x1 = *(const float4*)(&smem[eA*LSTR + 32*kt + 8*g_ + 4]);
                xs[0]=x0.x; xs[1]=x0.y; xs[2]=x0.z; xs[3]=x0.w;
                xs[4]=x1.x; xs[5]=x1.y; xs[6]=x1.z; xs[7]=x1.w;
            }
            FragU ahu, alu;
            {
                unsigned ph[4], pl[4];
                #pragma unroll
                for (int p = 0; p < 4; ++p) {
                    unsigned h0, l0, h1, l1;
                    bf16split(xs[2*p],     h0, l0);
                    bf16split(xs[2*p + 1], h1, l1);
                    ph[p] = h0 | (h1 << 16);
                    pl[p] = l0 | (l1 << 16);
                }
                ahu.u = make_uint4(ph[0], ph[1], ph[2], ph[3]);
                alu.u = make_uint4(pl[0], pl[1], pl[2], pl[3]);
            }
            const short8v ah = ahu.v, al = alu.v;
            const size_t kb = (size_t)(kt * 8) * 512 + (size_t)lane * 8;
            #pragma unroll
            for (int nb = 0; nb < 8; ++nb) {
                const short8v bh = *(const short8v*)(fH1 + kb + nb * 512);
                const short8v bl = *(const short8v*)(fL1 + kb + nb * 512);
                acc2[nb] = __builtin_amdgcn_mfma_f32_16x16x32_bf16(ah, bh, acc2[nb], 0, 0, 0);
                acc2[nb] = __builtin_amdgcn_mfma_f32_16x16x32_bf16(ah, bl, acc2[nb], 0, 0, 0);
                acc2[nb] = __builtin_amdgcn_mfma_f32_16x16x32_bf16(al, bh, acc2[nb], 0, 0, 0);
            }
        }
    }
    __syncthreads();   // all len reads done; act region may now be written

    // ---------- Phase 3: b1 + LayerNorm + SiLU in registers, store act ------
    // C-layout: acc2[nb][r] = h[edge 16w+4g_+r][col 16nb+s_].
    {
        float hv[8][4];
        float sum[4] = {0.f, 0.f, 0.f, 0.f};
        float sq [4] = {0.f, 0.f, 0.f, 0.f};
        #pragma unroll
        for (int nb = 0; nb < 8; ++nb) {
            const float b1v = b1[16*nb + s_];
            #pragma unroll
            for (int r = 0; r < 4; ++r) {
                const float v = acc2[nb][r] + b1v;
                hv[nb][r] = v;
                sum[r] += v;
                sq [r] += v * v;
            }
        }
        float mu[4], iv[4];
        #pragma unroll
        for (int r = 0; r < 4; ++r) {
            float s1 = sum[r], s2 = sq[r];
            s1 += __shfl_xor(s1, 1); s1 += __shfl_xor(s1, 2);
            s1 += __shfl_xor(s1, 4); s1 += __shfl_xor(s1, 8);
            s2 += __shfl_xor(s2, 1); s2 += __shfl_xor(s2, 2);
            s2 += __shfl_xor(s2, 4); s2 += __shfl_xor(s2, 8);
            mu[r] = s1 * (1.0f / HID);
            float var = s2 * (1.0f / HID) - mu[r] * mu[r];
            var = fmaxf(var, 0.0f);
            iv[r] = rsqrtf(var + 1e-5f);
        }
        const int rowb = wv_ * 16 + 4 * g_;
        #pragma unroll
        for (int nb = 0; nb < 8; ++nb) {
            const float gv  = g [16*nb + s_];
            const float bev = be[16*nb + s_];
            #pragma unroll
            for (int r = 0; r < 4; ++r) {
                const float hn = (hv[nb][r] - mu[r]) * iv[r] * gv + bev;
                const float sl = hn / (1.0f + __expf(-hn));
                smem[(rowb + r) * ASTR + 16*nb + s_] = sl;   // 2-way, free
            }
        }
    }
    __syncthreads();

    // ---------- Phase 4: w = silu @ W2 via split-bf16 MFMA ----------
    floatx4 acc[16];
    #pragma unroll
    for (int nb = 0; nb < 16; ++nb) {
        acc[nb][0] = 0.f; acc[nb][1] = 0.f; acc[nb][2] = 0.f; acc[nb][3] = 0.f;
    }
    {
        const int eA = wv_ * 16 + s_;
        const unsigned short* __restrict__ fH = fragW + (size_t)pipe * 32768;
        const unsigned short* __restrict__ fL = fH + FRAG_HI_SHORTS;
        for (int kt = 0; kt < 4; ++kt) {
            float xs[8];
            {
                const float4 x0 = *(const float4*)(&smem[eA*ASTR + 32*kt + 8*g_]);
                const float4 x1 = *(const float4*)(&smem[eA*ASTR + 32*kt + 8*g_ + 4]);
                xs[0]=x0.x; xs[1]=x0.y; xs[2]=x0.z; xs[3]=x0.w;
                xs[4]=x1.x; xs[5]=x1.y; xs[6]=x1.z; xs[7]=x1.w;
            }
            FragU ahu, alu;
            {
                unsigned ph[4], pl[4];
                #pragma unroll
                for (int p = 0; p < 4; ++p) {
                    unsigned h0, l0, h1, l1;
                    bf16split(xs[2*p],     h0, l0);
                    bf16split(xs[2*p + 1], h1, l1);
                    ph[p] = h0 | (h1 << 16);
                    pl[p] = l0 | (l1 << 16);
                }
                ahu.u = make_uint4(ph[0], ph[1], ph[2], ph[3]);
                alu.u = make_uint4(pl[0], pl[1], pl[2], pl[3]);
            }
            const short8v ah = ahu.v, al = alu.v;
            const size_t kb = (size_t)(kt * 16) * 512 + (size_t)lane * 8;
            #pragma unroll
            for (int nb = 0; nb < 16; ++nb) {
                const short8v bh = *(const short8v*)(fH + kb + nb * 512);
                const short8v bl = *(const short8v*)(fL + kb + nb * 512);
                acc[nb] = __builtin_amdgcn_mfma_f32_16x16x32_bf16(ah, bh, acc[nb], 0, 0, 0);
                acc[nb] = __builtin_amdgcn_mfma_f32_16x16x32_bf16(ah, bl, acc[nb], 0, 0, 0);
                acc[nb] = __builtin_amdgcn_mfma_f32_16x16x32_bf16(al, bh, acc[nb], 0, 0, 0);
            }
        }
    }
    __syncthreads();   // all act reads done; region becomes epilogue stage

    // ---------- Epilogue: DTP from C-layout; 2 r-iterations per barrier -----
    // (refcheck'd algebra from r18; stage = [2 r][4 g-groups][196] per wave)
    {
        const float c2 = 0.70710678118654752f;   // 1/sqrt(2)
        const float c3 = 0.40824829046386302f;   // 1/sqrt(6)
        float* sStage = smem + wv_ * 1568;       // 6272 B per wave, disjoint
        for (int rp = 0; rp < 2; ++rp) {
            #pragma unroll
            for (int rr = 0; rr < 2; ++rr) {
                const int r = rp * 2 + rr;
                const long e = e0 + wv_ * 16 + 4 * g_ + r;
                const float4 y = *(const float4*)(vec + e * 4);
                const float* __restrict__ fr   = fea  + e * (size_t)FEA;
                float* __restrict__       orow = outp + e * (size_t)FEA;
                #pragma unroll
                for (int q = 0; q < 4; ++q) {
                    const int u = 16 * q + s_;
                    const float w1 = acc[q     ][r];
                    const float w2 = acc[q + 4 ][r];
                    const float w3 = acc[q + 8 ][r];
                    const float w4 = acc[q + 12][r];
                    const float x0  = fr[u];
                    const float x1a = fr[64 + 3*u + 0];
                    const float x1b = fr[64 + 3*u + 1];
                    const float x1c = fr[64 + 3*u + 2];
                    const float dot = x1a*y.y + x1b*y.z + x1c*y.w;
                    orow[u] = w1*x0*y.x*c2 + w4*dot*c3;
                    sStage[rr*784 + g_*196 + 3*u + 0] = (w2*x0*y.y + w3*x1a*y.x) * c2;
                    sStage[rr*784 + g_*196 + 3*u + 1] = (w2*x0*y.z + w3*x1b*y.x) * c2;
                    sStage[rr*784 + g_*196 + 3*u + 2] = (w2*x0*y.w + w3*x1c*y.x) * c2;
                }
            }
            __syncthreads();   // stage complete (convergent: all waves, all rp)
            #pragma unroll
            for (int rr = 0; rr < 2; ++rr)
                #pragma unroll
                for (int dd = 0; dd < 3; ++dd) {
                    const int flat = dd * 256 + lane * 4;     // 0..764
                    const int eloc = flat / 192;              // 0..3 (g-group)
                    const int pos  = flat % 192;              // 16B aligned
                    const float4 v = *(const float4*)(&sStage[rr*784 + eloc*196 + pos]);
                    *(float4*)(&outp[(e0 + wv_*16 + 4*eloc + rp*2 + rr) * (size_t)FEA + 64 + pos]) = v;
                }
            __syncthreads();   // drain complete before next rp overwrites
        }
    }
}

extern "C" void kernel_launch(void* const* d_in, const int* in_sizes, int n_in,
                              void* d_out, int out_size, void* d_ws, size_t ws_size,
                              hipStream_t stream) {
    (void)in_sizes; (void)n_in; (void)ws_size; (void)out_size;
    const float* fea_a = (const float*)d_in[0];
    const float* vec_a = (const float*)d_in[1];
    const float* len_a = (const float*)d_in[2];
    const float* W1_a  = (const float*)d_in[3];
    const float* b1_a  = (const float*)d_in[4];
    const float* g_a   = (const float*)d_in[5];
    const float* be_a  = (const float*)d_in[6];
    const float* W2_a  = (const float*)d_in[7];
    const float* fea_b = (const float*)d_in[8];
    const float* vec_b = (const float*)d_in[9];
    const float* len_b = (const float*)d_in[10];
    const float* W1_b  = (const float*)d_in[11];
    const float* b1_b  = (const float*)d_in[12];
    const float* g_b   = (const float*)d_in[13];
    const float* be_b  = (const float*)d_in[14];
    const float* W2_b  = (const float*)d_in[15];
    float* out = (float*)d_out;
    unsigned short* frag = (unsigned short*)d_ws;   // needs 320 KB

    hipLaunchKernelGGL(prep_w2, dim3(16, 4, 2), dim3(64), 0, stream,
                       W2_a, W2_b, frag);
    hipLaunchKernelGGL(prep_w1, dim3(8, 2, 2), dim3(64), 0, stream,
                       W1_a, W1_b, frag);

    dim3 grid(E_N / EPB, 2);
    dim3 block(NT);
    hipLaunchKernelGGL(fused_mlp_dtp, grid, block, 0, stream,
                       fea_a, vec_a, len_a, b1_a, g_a, be_a,
                       fea_b, vec_b, len_b, b1_b, g_b, be_b,
                       frag, out);
}

// Round 20
// 181.192 us; speedup vs baseline: 1.1042x; 1.0516x over previous
//
#include <hip/hip_runtime.h>

namespace {
constexpr int E_N  = 131072;
constexpr int FEA  = 256;
constexpr int RAD  = 64;
constexpr int HID  = 128;
constexpr int WN   = 256;
constexpr int EPB  = 64;    // edges per block
constexpr int NT   = 256;   // 4 waves
constexpr int LSTR = 68;    // len tile stride (floats), 16B-aligned
constexpr int ASTR = 132;   // act stride (floats), 16B-aligned rows
constexpr int SMEMF = EPB * ASTR;        // 8448 floats = 33792 B time-aliased
constexpr int FRAG_HI_SHORTS = 2 * 4 * 16 * 64 * 8;  // 65536: W2 hi, both pipes
constexpr int W1HI = 2 * FRAG_HI_SHORTS;             // 131072: W1 hi base
constexpr int W1LO_DELTA = 2 * 2 * 8 * 64 * 8;       // 16384 shorts
}

typedef short short8v __attribute__((ext_vector_type(8)));   // 8 bf16 (4 VGPRs)
typedef float floatx4 __attribute__((ext_vector_type(4)));   // MFMA accumulator

__device__ __forceinline__ unsigned bf16rne(float x) {       // f32 -> bf16 (RNE)
    const unsigned u = __float_as_uint(x);
    return (u + 0x7FFFu + ((u >> 16) & 1u)) >> 16;
}
__device__ __forceinline__ float bf16tof(unsigned h) {
    return __uint_as_float(h << 16);
}
__device__ __forceinline__ void bf16split(float x, unsigned& hi, unsigned& lo) {
    hi = bf16rne(x);
    lo = bf16rne(x - bf16tof(hi));
}

union FragU { uint4 u; short8v v; };

// ---- Prep: split W2 into bf16 hi/lo MFMA B-fragments in d_ws ----
// lane = s + 16*g holds k = 32*kt + 8*g + j, column nb*16 + s.
__global__ __launch_bounds__(64)
void prep_w2(const float* __restrict__ W2a, const float* __restrict__ W2b,
             unsigned short* __restrict__ frag)
{
    const int lane = threadIdx.x;
    const int nb = blockIdx.x, kt = blockIdx.y, pipe = blockIdx.z;
    const float* __restrict__ W2 = pipe ? W2b : W2a;
    const int g = lane >> 4, s = lane & 15;
    unsigned ph[4], pl[4];
    #pragma unroll
    for (int p = 0; p < 4; ++p) {
        const float x0 = W2[(size_t)(32*kt + 8*g + 2*p)     * WN + nb*16 + s];
        const float x1 = W2[(size_t)(32*kt + 8*g + 2*p + 1) * WN + nb*16 + s];
        unsigned h0, l0, h1, l1;
        bf16split(x0, h0, l0);
        bf16split(x1, h1, l1);
        ph[p] = h0 | (h1 << 16);
        pl[p] = l0 | (l1 << 16);
    }
    const size_t fi = (size_t)pipe * 32768 + (size_t)((kt*16 + nb)*64 + lane) * 8;
    *(uint4*)(frag + fi)                  = make_uint4(ph[0], ph[1], ph[2], ph[3]);
    *(uint4*)(frag + FRAG_HI_SHORTS + fi) = make_uint4(pl[0], pl[1], pl[2], pl[3]);
}

// ---- Prep: split W1 into bf16 hi/lo MFMA B-fragments (same convention) ----
__global__ __launch_bounds__(64)
void prep_w1(const float* __restrict__ W1a, const float* __restrict__ W1b,
             unsigned short* __restrict__ frag)
{
    const int lane = threadIdx.x;
    const int nb = blockIdx.x, kt = blockIdx.y, pipe = blockIdx.z;
    const float* __restrict__ W1 = pipe ? W1b : W1a;
    const int g = lane >> 4, s = lane & 15;
    unsigned ph[4], pl[4];
    #pragma unroll
    for (int p = 0; p < 4; ++p) {
        const float x0 = W1[(size_t)(32*kt + 8*g + 2*p)     * HID + nb*16 + s];
        const float x1 = W1[(size_t)(32*kt + 8*g + 2*p + 1) * HID + nb*16 + s];
        unsigned h0, l0, h1, l1;
        bf16split(x0, h0, l0);
        bf16split(x1, h1, l1);
        ph[p] = h0 | (h1 << 16);
        pl[p] = l0 | (l1 << 16);
    }
    const size_t fi = (size_t)W1HI + (size_t)pipe * 8192
                    + (size_t)((kt*8 + nb)*64 + lane) * 8;
    *(uint4*)(frag + fi)              = make_uint4(ph[0], ph[1], ph[2], ph[3]);
    *(uint4*)(frag + W1LO_DELTA + fi) = make_uint4(pl[0], pl[1], pl[2], pl[3]);
}

__global__ __launch_bounds__(NT, 4)
void fused_mlp_dtp(
    const float* __restrict__ fea_a, const float* __restrict__ vec_a,
    const float* __restrict__ len_a, const float* __restrict__ b1_a,
    const float* __restrict__ g_a,   const float* __restrict__ be_a,
    const float* __restrict__ fea_b, const float* __restrict__ vec_b,
    const float* __restrict__ len_b, const float* __restrict__ b1_b,
    const float* __restrict__ g_b,   const float* __restrict__ be_b,
    const unsigned short* __restrict__ fragW,
    float* __restrict__ out)
{
    // Time-aliased LDS (33792 B): len[64][68] -> act[64][132] -> epi stage
    __shared__ __align__(16) float smem[SMEMF];

    const int pipe = blockIdx.y;
    const float* __restrict__ fea = pipe ? fea_b : fea_a;
    const float* __restrict__ vec = pipe ? vec_b : vec_a;
    const float* __restrict__ len = pipe ? len_b : len_a;
    const float* __restrict__ b1  = pipe ? b1_b  : b1_a;
    const float* __restrict__ g   = pipe ? g_b   : g_a;
    const float* __restrict__ be  = pipe ? be_b  : be_a;
    float* __restrict__ outp = out + (size_t)pipe * (size_t)E_N * FEA;

    const int t    = threadIdx.x;
    const int lane = t & 63;
    const int wv_  = t >> 6;
    const int s_   = lane & 15, g_ = lane >> 4;
    const long e0  = (long)blockIdx.x * EPB;

    // ---------- Phase 1: stage len tile [64][68] ----------
    {
        const float4* __restrict__ src = (const float4*)(len + e0 * RAD);
        #pragma unroll
        for (int i = 0; i < (EPB * RAD / 4) / NT; ++i) {
            const int f = t + i * NT;            // 0..1023
            const float4 v = src[f];
            const int e = f >> 4, kq = (f & 15) * 4;
            *(float4*)(&smem[e * LSTR + kq]) = v;
        }
    }
    __syncthreads();

    // ---------- Phase 2: h = len @ W1 via split-bf16 MFMA ----------
    // Wave owns edges [16w,16w+16); acc2[nb] covers cols [16nb,16nb+16).
    floatx4 acc2[8];
    #pragma unroll
    for (int nb = 0; nb < 8; ++nb) {
        acc2[nb][0] = 0.f; acc2[nb][1] = 0.f; acc2[nb][2] = 0.f; acc2[nb][3] = 0.f;
    }
    {
        const int eA = wv_ * 16 + s_;
        const unsigned short* __restrict__ fH1 = fragW + W1HI + (size_t)pipe * 8192;
        const unsigned short* __restrict__ fL1 = fH1 + W1LO_DELTA;
        #pragma unroll
        for (int kt = 0; kt < 2; ++kt) {
            float xs[8];
            {
                const float4 x0 = *(const float4*)(&smem[eA*LSTR + 32*kt + 8*g_]);
                const float4 x1 = *(const float4*)(&smem[eA*LSTR + 32*kt + 8*g_ + 4]);
                xs[0]=x0.x; xs[1]=x0.y; xs[2]=x0.z; xs[3]=x0.w;
                xs[4]=x1.x; xs[5]=x1.y; xs[6]=x1.z; xs[7]=x1.w;
            }
            FragU ahu, alu;
            {
                unsigned ph[4], pl[4];
                #pragma unroll
                for (int p = 0; p < 4; ++p) {
                    unsigned h0, l0, h1, l1;
                    bf16split(xs[2*p],     h0, l0);
                    bf16split(xs[2*p + 1], h1, l1);
                    ph[p] = h0 | (h1 << 16);
                    pl[p] = l0 | (l1 << 16);
                }
                ahu.u = make_uint4(ph[0], ph[1], ph[2], ph[3]);
                alu.u = make_uint4(pl[0], pl[1], pl[2], pl[3]);
            }
            const short8v ah = ahu.v, al = alu.v;
            const size_t kb = (size_t)(kt * 8) * 512 + (size_t)lane * 8;
            #pragma unroll
            for (int nb = 0; nb < 8; ++nb) {
                const short8v bh = *(const short8v*)(fH1 + kb + nb * 512);
                const short8v bl = *(const short8v*)(fL1 + kb + nb * 512);
                acc2[nb] = __builtin_amdgcn_mfma_f32_16x16x32_bf16(ah, bh, acc2[nb], 0, 0, 0);
                acc2[nb] = __builtin_amdgcn_mfma_f32_16x16x32_bf16(ah, bl, acc2[nb], 0, 0, 0);
                acc2[nb] = __builtin_amdgcn_mfma_f32_16x16x32_bf16(al, bh, acc2[nb], 0, 0, 0);
            }
        }
    }
    __syncthreads();   // all len reads done; act region may now be written

    // ---------- Phase 3: b1 + LayerNorm + SiLU in REGISTERS, scatter act ----
    // C-layout: acc2[nb][r] = h[edge wv*16+4g_+r][col 16nb+s_].
    // Row reduce = in-lane over nb + shfl_xor(1,2,4,8) over the s_ group.
    {
        float hv[8][4];
        float sum[4] = {0.f, 0.f, 0.f, 0.f};
        float sq [4] = {0.f, 0.f, 0.f, 0.f};
        #pragma unroll
        for (int nb = 0; nb < 8; ++nb) {
            const float b1v = b1[16*nb + s_];
            #pragma unroll
            for (int r = 0; r < 4; ++r) {
                const float v = acc2[nb][r] + b1v;
                hv[nb][r] = v;
                sum[r] += v;
                sq [r] += v * v;
            }
        }
        float mu[4], iv[4];
        #pragma unroll
        for (int r = 0; r < 4; ++r) {
            float s1 = sum[r], s2 = sq[r];
            s1 += __shfl_xor(s1, 1); s1 += __shfl_xor(s1, 2);
            s1 += __shfl_xor(s1, 4); s1 += __shfl_xor(s1, 8);
            s2 += __shfl_xor(s2, 1); s2 += __shfl_xor(s2, 2);
            s2 += __shfl_xor(s2, 4); s2 += __shfl_xor(s2, 8);
            mu[r] = s1 * (1.0f / HID);
            float var = s2 * (1.0f / HID) - mu[r] * mu[r];
            var = fmaxf(var, 0.0f);
            iv[r] = rsqrtf(var + 1e-5f);
        }
        const int rowb = wv_ * 16 + 4 * g_;
        #pragma unroll
        for (int nb = 0; nb < 8; ++nb) {
            const float gv  = g [16*nb + s_];
            const float bev = be[16*nb + s_];
            #pragma unroll
            for (int r = 0; r < 4; ++r) {
                const float hn = (hv[nb][r] - mu[r]) * iv[r] * gv + bev;
                const float sl = hn / (1.0f + __expf(-hn));
                smem[(rowb + r) * ASTR + 16*nb + s_] = sl;   // 2-way, free
            }
        }
    }
    __syncthreads();

    // ---------- Phase 4: w = silu @ W2 via split-bf16 MFMA (proven r13) -----
    floatx4 acc[16];
    #pragma unroll
    for (int nb = 0; nb < 16; ++nb) {
        acc[nb][0] = 0.f; acc[nb][1] = 0.f; acc[nb][2] = 0.f; acc[nb][3] = 0.f;
    }
    {
        const int eA = wv_ * 16 + s_;
        const unsigned short* __restrict__ fH = fragW + (size_t)pipe * 32768;
        const unsigned short* __restrict__ fL = fH + FRAG_HI_SHORTS;
        for (int kt = 0; kt < 4; ++kt) {
            float xs[8];
            {
                const float4 x0 = *(const float4*)(&smem[eA*ASTR + 32*kt + 8*g_]);
                const float4 x1 = *(const float4*)(&smem[eA*ASTR + 32*kt + 8*g_ + 4]);
                xs[0]=x0.x; xs[1]=x0.y; xs[2]=x0.z; xs[3]=x0.w;
                xs[4]=x1.x; xs[5]=x1.y; xs[6]=x1.z; xs[7]=x1.w;
            }
            FragU ahu, alu;
            {
                unsigned ph[4], pl[4];
                #pragma unroll
                for (int p = 0; p < 4; ++p) {
                    unsigned h0, l0, h1, l1;
                    bf16split(xs[2*p],     h0, l0);
                    bf16split(xs[2*p + 1], h1, l1);
                    ph[p] = h0 | (h1 << 16);
                    pl[p] = l0 | (l1 << 16);
                }
                ahu.u = make_uint4(ph[0], ph[1], ph[2], ph[3]);
                alu.u = make_uint4(pl[0], pl[1], pl[2], pl[3]);
            }
            const short8v ah = ahu.v, al = alu.v;
            const size_t kb = (size_t)(kt * 16) * 512 + (size_t)lane * 8;
            #pragma unroll
            for (int nb = 0; nb < 16; ++nb) {
                const short8v bh = *(const short8v*)(fH + kb + nb * 512);
                const short8v bl = *(const short8v*)(fL + kb + nb * 512);
                acc[nb] = __builtin_amdgcn_mfma_f32_16x16x32_bf16(ah, bh, acc[nb], 0, 0, 0);
                acc[nb] = __builtin_amdgcn_mfma_f32_16x16x32_bf16(ah, bl, acc[nb], 0, 0, 0);
                acc[nb] = __builtin_amdgcn_mfma_f32_16x16x32_bf16(al, bh, acc[nb], 0, 0, 0);
            }
        }
    }
    __syncthreads();   // all act reads done; region becomes epilogue stage

    // ---------- Epilogue: DTP from C-layout (proven r13) ----------
    {
        const float c2 = 0.70710678118654752f;   // 1/sqrt(2)
        const float c3 = 0.40824829046386302f;   // 1/sqrt(6)
        float* sStage = smem + wv_ * 784;        // [4 rows][196], per-wave
        for (int r = 0; r < 4; ++r) {
            const long e = e0 + wv_ * 16 + 4 * g_ + r;
            const float4 y = *(const float4*)(vec + e * 4);
            const float* __restrict__ fr   = fea  + e * (size_t)FEA;
            float* __restrict__       orow = outp + e * (size_t)FEA;
            #pragma unroll
            for (int q = 0; q < 4; ++q) {
                const int u = 16 * q + s_;
                const float w1 = acc[q     ][r];
                const float w2 = acc[q + 4 ][r];
                const float w3 = acc[q + 8 ][r];
                const float w4 = acc[q + 12][r];
                const float x0  = fr[u];
                const float x1a = fr[64 + 3*u + 0];
                const float x1b = fr[64 + 3*u + 1];
                const float x1c = fr[64 + 3*u + 2];
                const float dot = x1a*y.y + x1b*y.z + x1c*y.w;
                orow[u] = w1*x0*y.x*c2 + w4*dot*c3;
                sStage[g_*196 + 3*u + 0] = (w2*x0*y.y + w3*x1a*y.x) * c2;
                sStage[g_*196 + 3*u + 1] = (w2*x0*y.z + w3*x1b*y.x) * c2;
                sStage[g_*196 + 3*u + 2] = (w2*x0*y.w + w3*x1c*y.x) * c2;
            }
            __syncthreads();   // stage complete (convergent: all waves, all r)
            #pragma unroll
            for (int rr = 0; rr < 3; ++rr) {
                const int flat = rr * 256 + lane * 4;     // 0..764
                const int eloc = flat / 192;              // 0..3 (g-group)
                const int pos  = flat % 192;              // 16B aligned
                const float4 v = *(const float4*)(&sStage[eloc * 196 + pos]);
                *(float4*)(&outp[(e0 + wv_*16 + 4*eloc + r) * (size_t)FEA + 64 + pos]) = v;
            }
            __syncthreads();   // drain complete before next r overwrites
        }
    }
}

extern "C" void kernel_launch(void* const* d_in, const int* in_sizes, int n_in,
                              void* d_out, int out_size, void* d_ws, size_t ws_size,
                              hipStream_t stream) {
    (void)in_sizes; (void)n_in; (void)ws_size; (void)out_size;
    const float* fea_a = (const float*)d_in[0];
    const float* vec_a = (const float*)d_in[1];
    const float* len_a = (const float*)d_in[2];
    const float* W1_a  = (const float*)d_in[3];
    const float* b1_a  = (const float*)d_in[4];
    const float* g_a   = (const float*)d_in[5];
    const float* be_a  = (const float*)d_in[6];
    const float* W2_a  = (const float*)d_in[7];
    const float* fea_b = (const float*)d_in[8];
    const float* vec_b = (const float*)d_in[9];
    const float* len_b = (const float*)d_in[10];
    const float* W1_b  = (const float*)d_in[11];
    const float* b1_b  = (const float*)d_in[12];
    const float* g_b   = (const float*)d_in[13];
    const float* be_b  = (const float*)d_in[14];
    const float* W2_b  = (const float*)d_in[15];
    float* out = (float*)d_out;
    unsigned short* frag = (unsigned short*)d_ws;   // needs 320 KB

    hipLaunchKernelGGL(prep_w2, dim3(16, 4, 2), dim3(64), 0, stream,
                       W2_a, W2_b, frag);
    hipLaunchKernelGGL(prep_w1, dim3(8, 2, 2), dim3(64), 0, stream,
                       W1_a, W1_b, frag);

    dim3 grid(E_N / EPB, 2);
    dim3 block(NT);
    hipLaunchKernelGGL(fused_mlp_dtp, grid, block, 0, stream,
                       fea_a, vec_a, len_a, b1_a, g_a, be_a,
                       fea_b, vec_b, len_b, b1_b, g_b, be_b,
                       frag, out);
}